// Round 11
// baseline (2636.402 us; speedup 1.0000x reference)
//
#include <hip/hip_runtime.h>
#include <hip/hip_bf16.h>

// Problem constants
#define BB 64
#define TT 512
#define DD 128
#define HH 256
#define G4 1024   // 4*H
#define CC 50

typedef __bf16 bf16x8 __attribute__((ext_vector_type(8)));
typedef float  f32x4  __attribute__((ext_vector_type(4)));
typedef _Float16 h16x2 __attribute__((ext_vector_type(2)));

#if defined(__has_builtin)
#if __has_builtin(__builtin_amdgcn_fdot2)
#define HAS_FDOT2 1
#endif
#endif

__device__ __forceinline__ float bl16(unsigned u) { return __uint_as_float(u << 16); }
__device__ __forceinline__ float bh16(unsigned u) { return __uint_as_float(u & 0xffff0000u); }

__device__ __forceinline__ float sigf(float x) {
    return 1.f / (1.f + __expf(-x));
}
__device__ __forceinline__ float tanh_s(float x) {
    float ax = fabsf(x);
    float e = __expf(-2.f * ax);
    float r = (1.f - e) / (1.f + e);
    return copysignf(r, x);
}

// 8-element f16 dot product chunk, f32 accumulate
__device__ __forceinline__ float dot8(float acc, uint4 w, uint4 h) {
#ifdef HAS_FDOT2
    acc = __builtin_amdgcn_fdot2(__builtin_bit_cast(h16x2, w.x),
                                 __builtin_bit_cast(h16x2, h.x), acc, false);
    acc = __builtin_amdgcn_fdot2(__builtin_bit_cast(h16x2, w.y),
                                 __builtin_bit_cast(h16x2, h.y), acc, false);
    acc = __builtin_amdgcn_fdot2(__builtin_bit_cast(h16x2, w.z),
                                 __builtin_bit_cast(h16x2, h.z), acc, false);
    acc = __builtin_amdgcn_fdot2(__builtin_bit_cast(h16x2, w.w),
                                 __builtin_bit_cast(h16x2, h.w), acc, false);
#else
    {
        h16x2 a = __builtin_bit_cast(h16x2, w.x), b = __builtin_bit_cast(h16x2, h.x);
        acc = fmaf((float)a.x, (float)b.x, acc); acc = fmaf((float)a.y, (float)b.y, acc);
        a = __builtin_bit_cast(h16x2, w.y); b = __builtin_bit_cast(h16x2, h.y);
        acc = fmaf((float)a.x, (float)b.x, acc); acc = fmaf((float)a.y, (float)b.y, acc);
        a = __builtin_bit_cast(h16x2, w.z); b = __builtin_bit_cast(h16x2, h.z);
        acc = fmaf((float)a.x, (float)b.x, acc); acc = fmaf((float)a.y, (float)b.y, acc);
        a = __builtin_bit_cast(h16x2, w.w); b = __builtin_bit_cast(h16x2, h.w);
        acc = fmaf((float)a.x, (float)b.x, acc); acc = fmaf((float)a.y, (float)b.y, acc);
    }
#endif
    return acc;
}

// ---------------------------------------------------------------------------
// Kernel 0: f32 -> bf16 conversion (8 elements/thread)
// ---------------------------------------------------------------------------
__global__ __launch_bounds__(256) void k_cvt(
    const float* __restrict__ src, __hip_bfloat16* __restrict__ dst, int n)
{
    int i = (blockIdx.x * 256 + threadIdx.x) * 8;
    if (i + 8 <= n) {
        float4 a = *(const float4*)(src + i);
        float4 b = *(const float4*)(src + i + 4);
        __hip_bfloat16 o[8];
        o[0] = __float2bfloat16(a.x); o[1] = __float2bfloat16(a.y);
        o[2] = __float2bfloat16(a.z); o[3] = __float2bfloat16(a.w);
        o[4] = __float2bfloat16(b.x); o[5] = __float2bfloat16(b.y);
        o[6] = __float2bfloat16(b.z); o[7] = __float2bfloat16(b.w);
        *(uint4*)(dst + i) = *(const uint4*)o;
    }
}

// ---------------------------------------------------------------------------
// Kernel 0b: pack W_hh (f32 [1024][256]) -> f16.
// Wp[((dir*32 + kc)*4 + g)*256 + j] = 8 f16 of row (g*256 + j), k in
// [8kc, 8kc+8).  k_lstm v15 thread tid = q*256+j consumes kc = q*8 + c.
// ---------------------------------------------------------------------------
__global__ __launch_bounds__(256) void k_pack(
    const float* __restrict__ Wf, const float* __restrict__ Wb,
    uint4* __restrict__ Wp)
{
    int blk = blockIdx.x;            // 256 blocks = dir*128 + kc*4 + g
    int g   = blk & 3;
    int kc  = (blk >> 2) & 31;
    int dir = blk >> 7;
    int j = threadIdx.x;
    int row = g * 256 + j;
    const float* src = (dir ? Wb : Wf) + (size_t)row * 256 + kc * 8;
    float4 a = *(const float4*)src;
    float4 b = *(const float4*)(src + 4);
    _Float16 o[8];
    o[0] = (_Float16)a.x; o[1] = (_Float16)a.y;
    o[2] = (_Float16)a.z; o[3] = (_Float16)a.w;
    o[4] = (_Float16)b.x; o[5] = (_Float16)b.y;
    o[6] = (_Float16)b.z; o[7] = (_Float16)b.w;
    Wp[((size_t)(dir * 32 + kc) * 4 + g) * 256 + j] = *(const uint4*)o;
}

// ---------------------------------------------------------------------------
// Kernel 1: xg = emb[words] @ W_ih^T + b, LDS-staged MFMA GEMM (unchanged).
// ---------------------------------------------------------------------------
__global__ __launch_bounds__(256, 2) void k_xg(
    const int* __restrict__ words,
    const float* __restrict__ embf,           // f32 [50000][128]
    const __hip_bfloat16* __restrict__ Wih,   // bf16 [2048][128] (fwd|bwd)
    const float* __restrict__ bfv, const float* __restrict__ bbv,
    __hip_bfloat16* __restrict__ xg)
{
    __shared__ __align__(16) __hip_bfloat16 A[64][136];
    int tid = threadIdx.x;
    int bt0 = blockIdx.x * 64;

    {
        int r = tid >> 2;
        int c0 = (tid & 3) * 32;
        int word = words[bt0 + r];
        const float* src = embf + (size_t)word * DD + c0;
#pragma unroll
        for (int i = 0; i < 8; ++i) {
            float4 v = *(const float4*)(src + i * 4);
            __hip_bfloat16 o[4] = {__float2bfloat16(v.x), __float2bfloat16(v.y),
                                   __float2bfloat16(v.z), __float2bfloat16(v.w)};
            *(uint2*)&A[r][c0 + i * 4] = *(const uint2*)o;
        }
    }
    __syncthreads();

    int wave = tid >> 6, lane = tid & 63;
    int m = lane & 15, quad = lane >> 4;

    bf16x8 afr[4][4];
#pragma unroll
    for (int ms = 0; ms < 4; ++ms)
#pragma unroll
        for (int kf = 0; kf < 4; ++kf)
            afr[ms][kf] = *(const bf16x8*)&A[ms * 16 + m][quad * 8 + kf * 32];

#pragma unroll 1
    for (int i = 0; i < 32; ++i) {
        int nt = wave * 32 + i;
        int gate_g = nt * 16 + m;            // 0..2047
        int dir = gate_g >> 10;
        int gate = gate_g & 1023;
        const __hip_bfloat16* brow = Wih + (size_t)gate_g * DD + quad * 8;
        bf16x8 bfr[4];
#pragma unroll
        for (int kf = 0; kf < 4; ++kf) bfr[kf] = *(const bf16x8*)(brow + kf * 32);
        float bv = dir ? bbv[gate] : bfv[gate];
        size_t dbase = (size_t)dir * (size_t)(BB * TT * G4);

#pragma unroll
        for (int ms = 0; ms < 4; ++ms) {
            f32x4 acc = {0.f, 0.f, 0.f, 0.f};
#pragma unroll
            for (int kf = 0; kf < 4; ++kf)
                acc = __builtin_amdgcn_mfma_f32_16x16x32_bf16(afr[ms][kf], bfr[kf], acc, 0, 0, 0);
#pragma unroll
            for (int r = 0; r < 4; ++r) {
                int btrow = bt0 + ms * 16 + quad * 4 + r;
                xg[dbase + (size_t)btrow * G4 + gate] = __float2bfloat16(acc[r] + bv);
            }
        }
    }
}

// ---------------------------------------------------------------------------
// Kernel 2: LSTM recurrence v15 — 4-way K-split, 16 waves/CU.
// Model: v7/v14's ~94 B/cy/CU L2 stream rate is a CONCURRENCY limit, not a
// port limit (evidence: v9 with the same 8 waves doing 2x work per CU got
// ~56 B/cy; throughput tracks independently-issuing waves). LDS caps us at
// 1 block/CU, so raise waves in-block: 1024 threads = 16 waves (4/SIMD).
// tid = q*256 + j: thread owns 4 gates of hidden j over K-quarter q.
//   - per thread 32 chunks: 24 streamed/step, 8 LDS-resident (128 KB)
//   - same stream bytes (384 KB/block/step), 2x the issuing waves
//   - 3-quarter partial reduction via pbuf (12 KB); LDS total 144 KB
// waves_per_eu(4,4): 128-VGPR cap; kernel kept lean (no dead reg arrays).
// Early exit at L (r7/r9-validated).
// ---------------------------------------------------------------------------
__global__ __launch_bounds__(1024)
__attribute__((amdgpu_waves_per_eu(4, 4)))
void k_lstm(
    const __hip_bfloat16* __restrict__ xg,     // [2][B*T][1024] bf16
    const uint4* __restrict__ Wp,              // f16 packed [2][32][4][256]
    const int* __restrict__ seq_len,
    __hip_bfloat16* __restrict__ hcat)         // [B*T][512]
{
    int b = blockIdx.x & 63;
    int dir = blockIdx.x >> 6;
    int tid = threadIdx.x;      // 0..1023
    int j   = tid & 255;
    int q   = tid >> 8;         // K-quarter this thread reduces

    __shared__ __align__(16) uint4 wlds[8 * 1024];        // 131072 B
    __shared__ __align__(16) _Float16 hbf[2][HH];         //   1024 B
    __shared__ float pbuf[3][4][HH];                      //  12288 B

    const uint4* Wd = Wp + (size_t)dir * (32 * 4 * 256);
    // thread (q,j): chunk (c,g) at Ws[(c*4 + g)*256], c in [0,8)
    const uint4* Ws = Wd + (size_t)(q * 8) * 4 * 256 + j;

    // LDS-resident: c = 6,7 (8 chunks/thread = 128 KB)
#pragma unroll
    for (int c = 6; c < 8; ++c)
#pragma unroll
        for (int g = 0; g < 4; ++g)
            wlds[((c - 6) * 4 + g) * 1024 + tid] = Ws[(c * 4 + g) * 256];

    if (q == 0) hbf[0][j] = (_Float16)0.f;
    float cc = 0.f;
    int L = seq_len[b];
    const __hip_bfloat16* xgb = xg + (size_t)dir * (size_t)(BB * TT * G4)
                                   + (size_t)b * TT * G4;

    int tc = dir ? (L - 1) : 0;
    float xv0 = 0.f, xv1 = 0.f, xv2 = 0.f, xv3 = 0.f;
    if (q == 0) {
        const __hip_bfloat16* xr = xgb + (size_t)tc * G4 + j;
        xv0 = __bfloat162float(xr[0]);   xv1 = __bfloat162float(xr[256]);
        xv2 = __bfloat162float(xr[512]); xv3 = __bfloat162float(xr[768]);
    }
    __syncthreads();

#pragma unroll 1
    for (int t = 0; t < L; ++t) {          // early exit: t>=L is masked out
        int cur = t & 1, nxt = cur ^ 1;
        int tn = t + 1;
        int tcn = dir ? ((tn < L) ? (L - 1 - tn) : tn) : tn;
        bool pf = (tn < L);
        __hip_bfloat16 p0, p1, p2, p3;
        if (q == 0 && pf) {
            const __hip_bfloat16* xr = xgb + (size_t)tcn * G4 + j;
            p0 = xr[0]; p1 = xr[256]; p2 = xr[512]; p3 = xr[768];
        }

        // launder offsets: keep stream loads (periodic addresses) and LDS
        // weight reads inside the t-loop (no LICM / no reg-caching attempts)
        unsigned off = 0, soff = 0;
        asm volatile("" : "+v"(off), "+v"(soff));
        const uint4* Wst = (const uint4*)((const char*)Ws + soff);

        const _Float16* hrow = &hbf[cur][q * 64];
        float a0 = 0.f, a1 = 0.f, a2 = 0.f, a3 = 0.f;

        // streamed chunks c = 0..5 (24 loads/thread, flat interleave --
        // the schedule shape the compiler pipelines best, per r4/r6)
#pragma unroll
        for (int c = 0; c < 6; ++c) {
            uint4 hv = *(const uint4*)(hrow + c * 8);    // wave-uniform bcast
            uint4 w0 = Wst[(c * 4 + 0) * 256];
            uint4 w1 = Wst[(c * 4 + 1) * 256];
            uint4 w2 = Wst[(c * 4 + 2) * 256];
            uint4 w3 = Wst[(c * 4 + 3) * 256];
            a0 = dot8(a0, w0, hv);
            a1 = dot8(a1, w1, hv);
            a2 = dot8(a2, w2, hv);
            a3 = dot8(a3, w3, hv);
        }
        // LDS-resident chunks c = 6,7
#pragma unroll
        for (int c = 6; c < 8; ++c) {
            uint4 hv = *(const uint4*)(hrow + c * 8);
            int m0 = (c - 6) * 4;
            uint4 w0 = wlds[(m0 + 0) * 1024 + tid + off];
            uint4 w1 = wlds[(m0 + 1) * 1024 + tid + off];
            uint4 w2 = wlds[(m0 + 2) * 1024 + tid + off];
            uint4 w3 = wlds[(m0 + 3) * 1024 + tid + off];
            a0 = dot8(a0, w0, hv);
            a1 = dot8(a1, w1, hv);
            a2 = dot8(a2, w2, hv);
            a3 = dot8(a3, w3, hv);
        }

        if (q) {
            pbuf[q - 1][0][j] = a0; pbuf[q - 1][1][j] = a1;
            pbuf[q - 1][2][j] = a2; pbuf[q - 1][3][j] = a3;
        }
        __syncthreads();

        if (q == 0) {
            float gi = a0 + pbuf[0][0][j] + pbuf[1][0][j] + pbuf[2][0][j] + xv0;
            float gf = a1 + pbuf[0][1][j] + pbuf[1][1][j] + pbuf[2][1][j] + xv1;
            float gg = a2 + pbuf[0][2][j] + pbuf[1][2][j] + pbuf[2][2][j] + xv2;
            float go = a3 + pbuf[0][3][j] + pbuf[1][3][j] + pbuf[2][3][j] + xv3;
            float i_ = sigf(gi), f_ = sigf(gf), G = tanh_s(gg), o_ = sigf(go);
            cc = f_ * cc + i_ * G;
            float h = o_ * tanh_s(cc);
            hbf[nxt][j] = (_Float16)h;
            hcat[((size_t)(b * TT + tc)) * (2 * HH) + dir * HH + j] = __float2bfloat16(h);
            if (pf) {
                xv0 = __bfloat162float(p0); xv1 = __bfloat162float(p1);
                xv2 = __bfloat162float(p2); xv3 = __bfloat162float(p3);
            }
        }
        tc = tcn;
        __syncthreads();
    }
}

// ---------------------------------------------------------------------------
// Kernel 3: feats = hcat @ fc_W^T + fc_b ; logits = log_softmax(feats)
// 4 rows per 256-thread block (one 64-lane wave-team per row).
// ---------------------------------------------------------------------------
__global__ __launch_bounds__(256) void k_fc(
    const __hip_bfloat16* __restrict__ hcat,
    const __hip_bfloat16* __restrict__ fcW,
    const float* __restrict__ fcb,
    float* __restrict__ logits)
{
    int team = threadIdx.x >> 6;   // 0..3
    int tid  = threadIdx.x & 63;
    int row  = blockIdx.x * 4 + team;
    __shared__ __align__(16) float hrow[4][2 * HH];
    __shared__ float fbuf[4][CC + 2];

    {
        uint4 v = *(const uint4*)(hcat + (size_t)row * (2 * HH) + tid * 8);
        float* d = &hrow[team][tid * 8];
        d[0] = bl16(v.x); d[1] = bh16(v.x);
        d[2] = bl16(v.y); d[3] = bh16(v.y);
        d[4] = bl16(v.z); d[5] = bh16(v.z);
        d[6] = bl16(v.w); d[7] = bh16(v.w);
    }
    __syncthreads();

    if (tid < CC) {
        float acc = fcb[tid];
        const uint4* wr = (const uint4*)(fcW + (size_t)tid * (2 * HH));
#pragma unroll 8
        for (int kc = 0; kc < 64; ++kc) {
            uint4 wv = wr[kc];
            float4 h0 = *(const float4*)&hrow[team][kc * 8];
            float4 h1 = *(const float4*)&hrow[team][kc * 8 + 4];
            acc = fmaf(bl16(wv.x), h0.x, acc); acc = fmaf(bh16(wv.x), h0.y, acc);
            acc = fmaf(bl16(wv.y), h0.z, acc); acc = fmaf(bh16(wv.y), h0.w, acc);
            acc = fmaf(bl16(wv.z), h1.x, acc); acc = fmaf(bh16(wv.z), h1.y, acc);
            acc = fmaf(bl16(wv.w), h1.z, acc); acc = fmaf(bh16(wv.w), h1.w, acc);
        }
        fbuf[team][tid] = acc;
    }
    __syncthreads();

    float m = -1e30f;
    for (int i = 0; i < CC; ++i) m = fmaxf(m, fbuf[team][i]);
    float s = 0.f;
    for (int i = 0; i < CC; ++i) s += __expf(fbuf[team][i] - m);
    float lns = __logf(s);
    if (tid < CC) logits[(size_t)row * CC + tid] = fbuf[team][tid] - m - lns;
}

// ---------------------------------------------------------------------------
// Kernel 4: CRF forward scan + gold score; per-batch loss -> loss_b[b]
// lg[t] row prefetched one iteration ahead (serial-scan critical path).
// ---------------------------------------------------------------------------
__global__ __launch_bounds__(256) void k_crf(
    const float* __restrict__ logits,
    const int* __restrict__ target,
    const int* __restrict__ seq_len,
    const float* __restrict__ trans,
    const float* __restrict__ start_s,
    const float* __restrict__ end_s,
    float* __restrict__ loss_b)
{
    const float L2E = 1.4426950408889634f;
    const float LN2 = 0.6931471805599453f;
    int b = blockIdx.x;
    int tid = threadIdx.x;
    int q = tid >> 6;
    int j = tid & 63;
    bool act = (j < CC);
    int L = seq_len[b];
    const float* lg = logits + (size_t)b * TT * CC;

    __shared__ float alpha2[64];
    __shared__ float mpart[4][64];
    __shared__ float spart[4][64];
    __shared__ float red[256];
    __shared__ float nbuf[CC + 2];

    int i0 = q * 13;
    int icnt = min(13, CC - i0);
    float treg[13];
    if (act) {
#pragma unroll
        for (int s = 0; s < 13; ++s)
            if (s < icnt) treg[s] = L2E * trans[(i0 + s) * CC + j];
    }
    if (q == 0 && act) alpha2[j] = L2E * (lg[j] + start_s[j]);
    __syncthreads();

    float v[13];
    float lgreg = 0.f;
    if (q == 0 && act) lgreg = lg[CC + j];          // row t=1
    for (int t = 1; t < L; ++t) {
        float lgnext = 0.f;
        if (q == 0 && act && (t + 1) < L)
            lgnext = lg[(size_t)(t + 1) * CC + j];  // prefetch next row

        float mq = -1e30f;
        if (act) {
#pragma unroll
            for (int s = 0; s < 13; ++s)
                if (s < icnt) { v[s] = alpha2[i0 + s] + treg[s]; mq = fmaxf(mq, v[s]); }
        }
        mpart[q][j] = mq;
        __syncthreads();
        float M = fmaxf(fmaxf(mpart[0][j], mpart[1][j]), fmaxf(mpart[2][j], mpart[3][j]));
        float sq = 0.f;
        if (act) {
#pragma unroll
            for (int s = 0; s < 13; ++s)
                if (s < icnt) sq += exp2f(v[s] - M);
        }
        spart[q][j] = sq;
        __syncthreads();
        if (q == 0 && act) {
            float S = spart[0][j] + spart[1][j] + spart[2][j] + spart[3][j];
            alpha2[j] = M + log2f(S) + L2E * lgreg;
        }
        lgreg = lgnext;
        __syncthreads();
    }

    if (q == 0 && act) nbuf[j] = alpha2[j] + L2E * end_s[j];

    float gp = 0.f;
    const int* tg = target + b * TT;
    for (int t = tid; t < TT; t += 256) {
        if (t < L) {
            int c = tg[t];
            gp += lg[(size_t)t * CC + c];
            if (t >= 1) gp += trans[tg[t - 1] * CC + c];
        }
    }
    red[tid] = gp;
    __syncthreads();

    if (tid == 0) {
        float m2 = -1e30f;
        for (int i = 0; i < CC; ++i) m2 = fmaxf(m2, nbuf[i]);
        float s2 = 0.f;
        for (int i = 0; i < CC; ++i) s2 += exp2f(nbuf[i] - m2);
        float norm_nat = (m2 + log2f(s2)) * LN2;
        float g = 0.f;
        for (int i = 0; i < 256; ++i) g += red[i];
        g += start_s[tg[0]] + end_s[tg[L - 1]];
        loss_b[b] = norm_nat - g;
    }
}

// Parallel final reduction (one wave)
__global__ void k_fin(const float* __restrict__ loss_b, float* __restrict__ out)
{
    int t = threadIdx.x;
    float v = loss_b[t];
#pragma unroll
    for (int o = 32; o > 0; o >>= 1) v += __shfl_down(v, o);
    if (t == 0) out[0] = v * (1.f / BB);
}

// ---------------------------------------------------------------------------
extern "C" void kernel_launch(void* const* d_in, const int* in_sizes, int n_in,
                              void* d_out, int out_size, void* d_ws, size_t ws_size,
                              hipStream_t stream)
{
    const int* words   = (const int*)d_in[0];
    const int* target  = (const int*)d_in[1];
    const int* seq_len = (const int*)d_in[2];
    const float* emb    = (const float*)d_in[3];
    const float* W_ih_f = (const float*)d_in[4];
    const float* W_hh_f = (const float*)d_in[5];
    const float* b_f    = (const float*)d_in[6];
    const float* W_ih_b = (const float*)d_in[7];
    const float* W_hh_b = (const float*)d_in[8];
    const float* b_b    = (const float*)d_in[9];
    const float* fc_W   = (const float*)d_in[10];
    const float* fc_b   = (const float*)d_in[11];
    const float* trans  = (const float*)d_in[12];
    const float* start_s= (const float*)d_in[13];
    const float* end_s  = (const float*)d_in[14];

    char* ws = (char*)d_ws;
    // workspace layout (bytes):
    //   xg     : 134217728                         @ 0
    //   hcat   :  33554432                         @ 134217728
    //   logits :   6553600                         @ 167772160
    //     (Wp f16 lstm pack, 1 MB, overlaps logits: consumed by k_lstm
    //      BEFORE k_fc writes logits)
    //   loss_b :       256                         @ 174325760
    //   wihall :    524288  (bf16 [2048][128])     @ 174326016
    //   fcw_bf :     51200                         @ 174850304
    __hip_bfloat16* xg     = (__hip_bfloat16*)ws;
    __hip_bfloat16* hcat   = (__hip_bfloat16*)(ws + 134217728);
    float*          logits = (float*)(ws + 167772160);
    uint4*          Wp     = (uint4*)(ws + 167772160);
    float*          loss_b = (float*)(ws + 174325760);
    __hip_bfloat16* wihall = (__hip_bfloat16*)(ws + 174326016);
    __hip_bfloat16* fcw_bf = (__hip_bfloat16*)(ws + 174850304);

    k_cvt<<<64,  256, 0, stream>>>(W_ih_f, wihall,          131072);
    k_cvt<<<64,  256, 0, stream>>>(W_ih_b, wihall + 131072, 131072);
    k_cvt<<<13,  256, 0, stream>>>(fc_W,   fcw_bf,          25600);
    k_pack<<<256, 256, 0, stream>>>(W_hh_f, W_hh_b, Wp);

    k_xg  <<<512, 256, 0, stream>>>(words, emb, wihall, b_f, b_b, xg);
    k_lstm<<<128, 1024, 0, stream>>>(xg, Wp, seq_len, hcat);
    k_fc  <<<8192, 256, 0, stream>>>(hcat, fcw_bf, fc_b, logits);
    k_crf <<<64, 256, 0, stream>>>(logits, target, seq_len, trans, start_s, end_s, loss_b);
    k_fin <<<1, 64, 0, stream>>>(loss_b, (float*)d_out);
}

// Round 12
// 1698.789 us; speedup vs baseline: 1.5519x; 1.5519x over previous
//
#include <hip/hip_runtime.h>
#include <hip/hip_bf16.h>

// Problem constants
#define BB 64
#define TT 512
#define DD 128
#define HH 256
#define G4 1024   // 4*H
#define CC 50

typedef __bf16 bf16x8 __attribute__((ext_vector_type(8)));
typedef float  f32x4  __attribute__((ext_vector_type(4)));
typedef _Float16 h16x2 __attribute__((ext_vector_type(2)));

#if defined(__has_builtin)
#if __has_builtin(__builtin_amdgcn_fdot2)
#define HAS_FDOT2 1
#endif
#endif

__device__ __forceinline__ float bl16(unsigned u) { return __uint_as_float(u << 16); }
__device__ __forceinline__ float bh16(unsigned u) { return __uint_as_float(u & 0xffff0000u); }

__device__ __forceinline__ float sigf(float x) {
    return 1.f / (1.f + __expf(-x));
}
__device__ __forceinline__ float tanh_s(float x) {
    float ax = fabsf(x);
    float e = __expf(-2.f * ax);
    float r = (1.f - e) / (1.f + e);
    return copysignf(r, x);
}

// 8-element f16 dot product chunk, f32 accumulate
__device__ __forceinline__ float dot8(float acc, uint4 w, uint4 h) {
#ifdef HAS_FDOT2
    acc = __builtin_amdgcn_fdot2(__builtin_bit_cast(h16x2, w.x),
                                 __builtin_bit_cast(h16x2, h.x), acc, false);
    acc = __builtin_amdgcn_fdot2(__builtin_bit_cast(h16x2, w.y),
                                 __builtin_bit_cast(h16x2, h.y), acc, false);
    acc = __builtin_amdgcn_fdot2(__builtin_bit_cast(h16x2, w.z),
                                 __builtin_bit_cast(h16x2, h.z), acc, false);
    acc = __builtin_amdgcn_fdot2(__builtin_bit_cast(h16x2, w.w),
                                 __builtin_bit_cast(h16x2, h.w), acc, false);
#else
    {
        h16x2 a = __builtin_bit_cast(h16x2, w.x), b = __builtin_bit_cast(h16x2, h.x);
        acc = fmaf((float)a.x, (float)b.x, acc); acc = fmaf((float)a.y, (float)b.y, acc);
        a = __builtin_bit_cast(h16x2, w.y); b = __builtin_bit_cast(h16x2, h.y);
        acc = fmaf((float)a.x, (float)b.x, acc); acc = fmaf((float)a.y, (float)b.y, acc);
        a = __builtin_bit_cast(h16x2, w.z); b = __builtin_bit_cast(h16x2, h.z);
        acc = fmaf((float)a.x, (float)b.x, acc); acc = fmaf((float)a.y, (float)b.y, acc);
        a = __builtin_bit_cast(h16x2, w.w); b = __builtin_bit_cast(h16x2, h.w);
        acc = fmaf((float)a.x, (float)b.x, acc); acc = fmaf((float)a.y, (float)b.y, acc);
    }
#endif
    return acc;
}

// ---------------------------------------------------------------------------
// Kernel 0: f32 -> bf16 conversion (8 elements/thread)
// ---------------------------------------------------------------------------
__global__ __launch_bounds__(256) void k_cvt(
    const float* __restrict__ src, __hip_bfloat16* __restrict__ dst, int n)
{
    int i = (blockIdx.x * 256 + threadIdx.x) * 8;
    if (i + 8 <= n) {
        float4 a = *(const float4*)(src + i);
        float4 b = *(const float4*)(src + i + 4);
        __hip_bfloat16 o[8];
        o[0] = __float2bfloat16(a.x); o[1] = __float2bfloat16(a.y);
        o[2] = __float2bfloat16(a.z); o[3] = __float2bfloat16(a.w);
        o[4] = __float2bfloat16(b.x); o[5] = __float2bfloat16(b.y);
        o[6] = __float2bfloat16(b.z); o[7] = __float2bfloat16(b.w);
        *(uint4*)(dst + i) = *(const uint4*)o;
    }
}

// ---------------------------------------------------------------------------
// Kernel 0b: pack W_hh (f32 [1024][256]) -> f16.
// Wp[((dir*32 + kc)*4 + g)*256 + j] = 8 f16 of row (g*256 + j), k in
// [8kc, 8kc+8).  k_lstm thread tid = half*256+j consumes kc = kcl + 16*half.
// ---------------------------------------------------------------------------
__global__ __launch_bounds__(256) void k_pack(
    const float* __restrict__ Wf, const float* __restrict__ Wb,
    uint4* __restrict__ Wp)
{
    int blk = blockIdx.x;            // 256 blocks = dir*128 + kc*4 + g
    int g   = blk & 3;
    int kc  = (blk >> 2) & 31;
    int dir = blk >> 7;
    int j = threadIdx.x;
    int row = g * 256 + j;
    const float* src = (dir ? Wb : Wf) + (size_t)row * 256 + kc * 8;
    float4 a = *(const float4*)src;
    float4 b = *(const float4*)(src + 4);
    _Float16 o[8];
    o[0] = (_Float16)a.x; o[1] = (_Float16)a.y;
    o[2] = (_Float16)a.z; o[3] = (_Float16)a.w;
    o[4] = (_Float16)b.x; o[5] = (_Float16)b.y;
    o[6] = (_Float16)b.z; o[7] = (_Float16)b.w;
    Wp[((size_t)(dir * 32 + kc) * 4 + g) * 256 + j] = *(const uint4*)o;
}

// ---------------------------------------------------------------------------
// Kernel 1: xg = emb[words] @ W_ih^T + b, LDS-staged MFMA GEMM (unchanged).
// ---------------------------------------------------------------------------
__global__ __launch_bounds__(256, 2) void k_xg(
    const int* __restrict__ words,
    const float* __restrict__ embf,           // f32 [50000][128]
    const __hip_bfloat16* __restrict__ Wih,   // bf16 [2048][128] (fwd|bwd)
    const float* __restrict__ bfv, const float* __restrict__ bbv,
    __hip_bfloat16* __restrict__ xg)
{
    __shared__ __align__(16) __hip_bfloat16 A[64][136];
    int tid = threadIdx.x;
    int bt0 = blockIdx.x * 64;

    {
        int r = tid >> 2;
        int c0 = (tid & 3) * 32;
        int word = words[bt0 + r];
        const float* src = embf + (size_t)word * DD + c0;
#pragma unroll
        for (int i = 0; i < 8; ++i) {
            float4 v = *(const float4*)(src + i * 4);
            __hip_bfloat16 o[4] = {__float2bfloat16(v.x), __float2bfloat16(v.y),
                                   __float2bfloat16(v.z), __float2bfloat16(v.w)};
            *(uint2*)&A[r][c0 + i * 4] = *(const uint2*)o;
        }
    }
    __syncthreads();

    int wave = tid >> 6, lane = tid & 63;
    int m = lane & 15, quad = lane >> 4;

    bf16x8 afr[4][4];
#pragma unroll
    for (int ms = 0; ms < 4; ++ms)
#pragma unroll
        for (int kf = 0; kf < 4; ++kf)
            afr[ms][kf] = *(const bf16x8*)&A[ms * 16 + m][quad * 8 + kf * 32];

#pragma unroll 1
    for (int i = 0; i < 32; ++i) {
        int nt = wave * 32 + i;
        int gate_g = nt * 16 + m;            // 0..2047
        int dir = gate_g >> 10;
        int gate = gate_g & 1023;
        const __hip_bfloat16* brow = Wih + (size_t)gate_g * DD + quad * 8;
        bf16x8 bfr[4];
#pragma unroll
        for (int kf = 0; kf < 4; ++kf) bfr[kf] = *(const bf16x8*)(brow + kf * 32);
        float bv = dir ? bbv[gate] : bfv[gate];
        size_t dbase = (size_t)dir * (size_t)(BB * TT * G4);

#pragma unroll
        for (int ms = 0; ms < 4; ++ms) {
            f32x4 acc = {0.f, 0.f, 0.f, 0.f};
#pragma unroll
            for (int kf = 0; kf < 4; ++kf)
                acc = __builtin_amdgcn_mfma_f32_16x16x32_bf16(afr[ms][kf], bfr[kf], acc, 0, 0, 0);
#pragma unroll
            for (int r = 0; r < 4; ++r) {
                int btrow = bt0 + ms * 16 + quad * 4 + r;
                xg[dbase + (size_t)btrow * G4 + gate] = __float2bfloat16(acc[r] + bv);
            }
        }
    }
}

// ---------------------------------------------------------------------------
// Kernel 2: LSTM recurrence v14 (RESTORED round-10 best: 890 us measured).
// Structure = round-3 v7 (flat interleaved stream; compiler pipelines it to
// the L2 rate of ~94 B/cy/CU) + early exit at L.
// The design space is bracketed on every axis around this point:
//   v9  (8 waves, 2x work/wave):  ~56 B/cy  -- worse
//   v15 (16 waves, .5x work/wave): ~45 B/cy (VGPR 52 -> no load pipeline)
//   v6/v7/v10 reg-residency: allocator refuses >128 VGPR of invariant data
//   v11/v12/v13 AGPR residency: read-back costs > stream savings
//   v8/v10/v15 hand pipelines: all lose to the compiler's flat schedule
// 890 us = 4170 cy/step = stream model within 4% -> structural roofline.
// ---------------------------------------------------------------------------
__global__ __launch_bounds__(512)
__attribute__((amdgpu_waves_per_eu(2, 2)))
void k_lstm(
    const __hip_bfloat16* __restrict__ xg,     // [2][B*T][1024] bf16
    const uint4* __restrict__ Wp,              // f16 packed [2][32][4][256]
    const int* __restrict__ seq_len,
    __hip_bfloat16* __restrict__ hcat)         // [B*T][512]
{
    int b = blockIdx.x & 63;
    int dir = blockIdx.x >> 6;
    int tid = threadIdx.x;      // 0..511
    int j   = tid & 255;
    int half = tid >> 8;        // K-half this thread reduces

    __shared__ __align__(16) uint4 wlds[16 * 512];        // 131072 B
    __shared__ __align__(16) _Float16 hbf[2][HH];         //   1024 B
    __shared__ float pbuf[4][HH];                         //   4096 B

    const uint4* Wd = Wp + (size_t)dir * (32 * 4 * 256);

    // register weights: kcl 0..11 (48 chunks = 192 VGPRs requested)
    uint4 wr[12][4];
#pragma unroll
    for (int kcl = 0; kcl < 12; ++kcl)
#pragma unroll
        for (int g = 0; g < 4; ++g)
            wr[kcl][g] = Wd[(((kcl + 16 * half) * 4 + g) * 256) + j];

    // LDS weights: kcl 12..15 (16 chunks), layout [m][tid]
#pragma unroll
    for (int kcl = 12; kcl < 16; ++kcl)
#pragma unroll
        for (int g = 0; g < 4; ++g)
            wlds[((kcl - 12) * 4 + g) * 512 + tid] =
                Wd[(((kcl + 16 * half) * 4 + g) * 256) + j];

    if (half == 0) hbf[0][j] = (_Float16)0.f;
    float c = 0.f;
    int L = seq_len[b];
    const __hip_bfloat16* xgb = xg + (size_t)dir * (size_t)(BB * TT * G4)
                                   + (size_t)b * TT * G4;

    int tc = dir ? (L - 1) : 0;
    float xv0 = 0.f, xv1 = 0.f, xv2 = 0.f, xv3 = 0.f;
    if (half == 0) {
        const __hip_bfloat16* xr = xgb + (size_t)tc * G4 + j;
        xv0 = __bfloat162float(xr[0]);   xv1 = __bfloat162float(xr[256]);
        xv2 = __bfloat162float(xr[512]); xv3 = __bfloat162float(xr[768]);
    }
    __syncthreads();

#pragma unroll 1
    for (int t = 0; t < L; ++t) {          // early exit: t>=L is masked out
        // --- loop-carried pin on the 48 weight chunks (round-3 v7 exact)
#pragma unroll
        for (int kcl = 0; kcl < 12; ++kcl)
#pragma unroll
            for (int g = 0; g < 4; ++g)
                asm volatile("" : "+v"(wr[kcl][g].x), "+v"(wr[kcl][g].y),
                                  "+v"(wr[kcl][g].z), "+v"(wr[kcl][g].w));

        int cur = t & 1, nxt = cur ^ 1;
        int tn = t + 1;
        int tcn = dir ? ((tn < L) ? (L - 1 - tn) : tn) : tn;
        bool pf = (tn < L);
        __hip_bfloat16 p0, p1, p2, p3;
        if (half == 0 && pf) {
            const __hip_bfloat16* xr = xgb + (size_t)tcn * G4 + j;
            p0 = xr[0]; p1 = xr[256]; p2 = xr[512]; p3 = xr[768];
        }

        // launder an offset so LDS weight reads can't be hoisted/cached
        unsigned off = 0;
        asm volatile("" : "+v"(off));

        const _Float16* hrow = &hbf[cur][half * 128];
        float a0 = 0.f, a1 = 0.f, a2 = 0.f, a3 = 0.f;
#pragma unroll
        for (int kcl = 0; kcl < 12; ++kcl) {
            uint4 hv = *(const uint4*)(hrow + kcl * 8);   // wave-uniform bcast
            a0 = dot8(a0, wr[kcl][0], hv);
            a1 = dot8(a1, wr[kcl][1], hv);
            a2 = dot8(a2, wr[kcl][2], hv);
            a3 = dot8(a3, wr[kcl][3], hv);
        }
#pragma unroll
        for (int kcl = 12; kcl < 16; ++kcl) {
            uint4 hv = *(const uint4*)(hrow + kcl * 8);
            int m0 = (kcl - 12) * 4;
            uint4 w0 = wlds[(m0 + 0) * 512 + tid + off];
            uint4 w1 = wlds[(m0 + 1) * 512 + tid + off];
            uint4 w2 = wlds[(m0 + 2) * 512 + tid + off];
            uint4 w3 = wlds[(m0 + 3) * 512 + tid + off];
            a0 = dot8(a0, w0, hv);
            a1 = dot8(a1, w1, hv);
            a2 = dot8(a2, w2, hv);
            a3 = dot8(a3, w3, hv);
            __builtin_amdgcn_sched_barrier(0);   // cap in-flight LDS chunks
        }

        if (half) {
            pbuf[0][j] = a0; pbuf[1][j] = a1;
            pbuf[2][j] = a2; pbuf[3][j] = a3;
        }
        __syncthreads();

        if (half == 0) {
            float gi = a0 + pbuf[0][j] + xv0;
            float gf = a1 + pbuf[1][j] + xv1;
            float gg = a2 + pbuf[2][j] + xv2;
            float go = a3 + pbuf[3][j] + xv3;
            float i_ = sigf(gi), f_ = sigf(gf), G = tanh_s(gg), o_ = sigf(go);
            c = f_ * c + i_ * G;
            float h = o_ * tanh_s(c);
            hbf[nxt][j] = (_Float16)h;
            hcat[((size_t)(b * TT + tc)) * (2 * HH) + dir * HH + j] = __float2bfloat16(h);
            if (pf) {
                xv0 = __bfloat162float(p0); xv1 = __bfloat162float(p1);
                xv2 = __bfloat162float(p2); xv3 = __bfloat162float(p3);
            }
        }
        tc = tcn;
        __syncthreads();
    }
}

// ---------------------------------------------------------------------------
// Kernel 3: feats = hcat @ fc_W^T + fc_b ; logits = log_softmax(feats)
// 4 rows per 256-thread block (one 64-lane wave-team per row).
// ---------------------------------------------------------------------------
__global__ __launch_bounds__(256) void k_fc(
    const __hip_bfloat16* __restrict__ hcat,
    const __hip_bfloat16* __restrict__ fcW,
    const float* __restrict__ fcb,
    float* __restrict__ logits)
{
    int team = threadIdx.x >> 6;   // 0..3
    int tid  = threadIdx.x & 63;
    int row  = blockIdx.x * 4 + team;
    __shared__ __align__(16) float hrow[4][2 * HH];
    __shared__ float fbuf[4][CC + 2];

    {
        uint4 v = *(const uint4*)(hcat + (size_t)row * (2 * HH) + tid * 8);
        float* d = &hrow[team][tid * 8];
        d[0] = bl16(v.x); d[1] = bh16(v.x);
        d[2] = bl16(v.y); d[3] = bh16(v.y);
        d[4] = bl16(v.z); d[5] = bh16(v.z);
        d[6] = bl16(v.w); d[7] = bh16(v.w);
    }
    __syncthreads();

    if (tid < CC) {
        float acc = fcb[tid];
        const uint4* wr = (const uint4*)(fcW + (size_t)tid * (2 * HH));
#pragma unroll 8
        for (int kc = 0; kc < 64; ++kc) {
            uint4 wv = wr[kc];
            float4 h0 = *(const float4*)&hrow[team][kc * 8];
            float4 h1 = *(const float4*)&hrow[team][kc * 8 + 4];
            acc = fmaf(bl16(wv.x), h0.x, acc); acc = fmaf(bh16(wv.x), h0.y, acc);
            acc = fmaf(bl16(wv.y), h0.z, acc); acc = fmaf(bh16(wv.y), h0.w, acc);
            acc = fmaf(bl16(wv.z), h1.x, acc); acc = fmaf(bh16(wv.z), h1.y, acc);
            acc = fmaf(bl16(wv.w), h1.z, acc); acc = fmaf(bh16(wv.w), h1.w, acc);
        }
        fbuf[team][tid] = acc;
    }
    __syncthreads();

    float m = -1e30f;
    for (int i = 0; i < CC; ++i) m = fmaxf(m, fbuf[team][i]);
    float s = 0.f;
    for (int i = 0; i < CC; ++i) s += __expf(fbuf[team][i] - m);
    float lns = __logf(s);
    if (tid < CC) logits[(size_t)row * CC + tid] = fbuf[team][tid] - m - lns;
}

// ---------------------------------------------------------------------------
// Kernel 4: CRF forward scan + gold score; per-batch loss -> loss_b[b]
// lg[t] row prefetched one iteration ahead (serial-scan critical path).
// ---------------------------------------------------------------------------
__global__ __launch_bounds__(256) void k_crf(
    const float* __restrict__ logits,
    const int* __restrict__ target,
    const int* __restrict__ seq_len,
    const float* __restrict__ trans,
    const float* __restrict__ start_s,
    const float* __restrict__ end_s,
    float* __restrict__ loss_b)
{
    const float L2E = 1.4426950408889634f;
    const float LN2 = 0.6931471805599453f;
    int b = blockIdx.x;
    int tid = threadIdx.x;
    int q = tid >> 6;
    int j = tid & 63;
    bool act = (j < CC);
    int L = seq_len[b];
    const float* lg = logits + (size_t)b * TT * CC;

    __shared__ float alpha2[64];
    __shared__ float mpart[4][64];
    __shared__ float spart[4][64];
    __shared__ float red[256];
    __shared__ float nbuf[CC + 2];

    int i0 = q * 13;
    int icnt = min(13, CC - i0);
    float treg[13];
    if (act) {
#pragma unroll
        for (int s = 0; s < 13; ++s)
            if (s < icnt) treg[s] = L2E * trans[(i0 + s) * CC + j];
    }
    if (q == 0 && act) alpha2[j] = L2E * (lg[j] + start_s[j]);
    __syncthreads();

    float v[13];
    float lgreg = 0.f;
    if (q == 0 && act) lgreg = lg[CC + j];          // row t=1
    for (int t = 1; t < L; ++t) {
        float lgnext = 0.f;
        if (q == 0 && act && (t + 1) < L)
            lgnext = lg[(size_t)(t + 1) * CC + j];  // prefetch next row

        float mq = -1e30f;
        if (act) {
#pragma unroll
            for (int s = 0; s < 13; ++s)
                if (s < icnt) { v[s] = alpha2[i0 + s] + treg[s]; mq = fmaxf(mq, v[s]); }
        }
        mpart[q][j] = mq;
        __syncthreads();
        float M = fmaxf(fmaxf(mpart[0][j], mpart[1][j]), fmaxf(mpart[2][j], mpart[3][j]));
        float sq = 0.f;
        if (act) {
#pragma unroll
            for (int s = 0; s < 13; ++s)
                if (s < icnt) sq += exp2f(v[s] - M);
        }
        spart[q][j] = sq;
        __syncthreads();
        if (q == 0 && act) {
            float S = spart[0][j] + spart[1][j] + spart[2][j] + spart[3][j];
            alpha2[j] = M + log2f(S) + L2E * lgreg;
        }
        lgreg = lgnext;
        __syncthreads();
    }

    if (q == 0 && act) nbuf[j] = alpha2[j] + L2E * end_s[j];

    float gp = 0.f;
    const int* tg = target + b * TT;
    for (int t = tid; t < TT; t += 256) {
        if (t < L) {
            int c = tg[t];
            gp += lg[(size_t)t * CC + c];
            if (t >= 1) gp += trans[tg[t - 1] * CC + c];
        }
    }
    red[tid] = gp;
    __syncthreads();

    if (tid == 0) {
        float m2 = -1e30f;
        for (int i = 0; i < CC; ++i) m2 = fmaxf(m2, nbuf[i]);
        float s2 = 0.f;
        for (int i = 0; i < CC; ++i) s2 += exp2f(nbuf[i] - m2);
        float norm_nat = (m2 + log2f(s2)) * LN2;
        float g = 0.f;
        for (int i = 0; i < 256; ++i) g += red[i];
        g += start_s[tg[0]] + end_s[tg[L - 1]];
        loss_b[b] = norm_nat - g;
    }
}

// Parallel final reduction (one wave)
__global__ void k_fin(const float* __restrict__ loss_b, float* __restrict__ out)
{
    int t = threadIdx.x;
    float v = loss_b[t];
#pragma unroll
    for (int o = 32; o > 0; o >>= 1) v += __shfl_down(v, o);
    if (t == 0) out[0] = v * (1.f / BB);
}

// ---------------------------------------------------------------------------
extern "C" void kernel_launch(void* const* d_in, const int* in_sizes, int n_in,
                              void* d_out, int out_size, void* d_ws, size_t ws_size,
                              hipStream_t stream)
{
    const int* words   = (const int*)d_in[0];
    const int* target  = (const int*)d_in[1];
    const int* seq_len = (const int*)d_in[2];
    const float* emb    = (const float*)d_in[3];
    const float* W_ih_f = (const float*)d_in[4];
    const float* W_hh_f = (const float*)d_in[5];
    const float* b_f    = (const float*)d_in[6];
    const float* W_ih_b = (const float*)d_in[7];
    const float* W_hh_b = (const float*)d_in[8];
    const float* b_b    = (const float*)d_in[9];
    const float* fc_W   = (const float*)d_in[10];
    const float* fc_b   = (const float*)d_in[11];
    const float* trans  = (const float*)d_in[12];
    const float* start_s= (const float*)d_in[13];
    const float* end_s  = (const float*)d_in[14];

    char* ws = (char*)d_ws;
    // workspace layout (bytes):
    //   xg     : 134217728                         @ 0
    //   hcat   :  33554432                         @ 134217728
    //   logits :   6553600                         @ 167772160
    //     (Wp f16 lstm pack, 1 MB, overlaps logits: consumed by k_lstm
    //      BEFORE k_fc writes logits)
    //   loss_b :       256                         @ 174325760
    //   wihall :    524288  (bf16 [2048][128])     @ 174326016
    //   fcw_bf :     51200                         @ 174850304
    __hip_bfloat16* xg     = (__hip_bfloat16*)ws;
    __hip_bfloat16* hcat   = (__hip_bfloat16*)(ws + 134217728);
    float*          logits = (float*)(ws + 167772160);
    uint4*          Wp     = (uint4*)(ws + 167772160);
    float*          loss_b = (float*)(ws + 174325760);
    __hip_bfloat16* wihall = (__hip_bfloat16*)(ws + 174326016);
    __hip_bfloat16* fcw_bf = (__hip_bfloat16*)(ws + 174850304);

    k_cvt<<<64,  256, 0, stream>>>(W_ih_f, wihall,          131072);
    k_cvt<<<64,  256, 0, stream>>>(W_ih_b, wihall + 131072, 131072);
    k_cvt<<<13,  256, 0, stream>>>(fc_W,   fcw_bf,          25600);
    k_pack<<<256, 256, 0, stream>>>(W_hh_f, W_hh_b, Wp);

    k_xg  <<<512, 256, 0, stream>>>(words, emb, wihall, b_f, b_b, xg);
    k_lstm<<<128, 512, 0, stream>>>(xg, Wp, seq_len, hcat);
    k_fc  <<<8192, 256, 0, stream>>>(hcat, fcw_bf, fc_b, logits);
    k_crf <<<64, 256, 0, stream>>>(logits, target, seq_len, trans, start_s, end_s, loss_b);
    k_fin <<<1, 64, 0, stream>>>(loss_b, (float*)d_out);
}